// Round 2
// baseline (182.058 us; speedup 1.0000x reference)
//
#include <hip/hip_runtime.h>

// Problem constants (fixed by the reference setup)
#define BB 2
#define NN 4096
#define EE 65536
#define MM 4
#define HH 256
#define CAP 32   // actual in-degree is exactly 16 per node; 32 gives safety margin
#define NPB 8    // nodes per block in the fused kernel

// ---------------------------------------------------------------------------
// Kernel 1: per-edge scalar coefficient  coeff[b,e] = edge_fts[b,e,:] . edge_W + edge_b
// One 64-lane wave per edge; lane l handles 4 consecutive floats (float4).
// ---------------------------------------------------------------------------
__global__ __launch_bounds__(256) void k_coeff(const float* __restrict__ edge_fts,
                                               const float* __restrict__ edge_W,
                                               const float* __restrict__ edge_b,
                                               float* __restrict__ coeff) {
  const int gid = blockIdx.x * blockDim.x + threadIdx.x;
  const int widx = gid >> 6;   // global wave index == flat edge index b*E+e
  const int lane = gid & 63;
  if (widx >= BB * EE) return;
  const float4 ef = *reinterpret_cast<const float4*>(edge_fts + (size_t)widx * HH + lane * 4);
  const float4 wv = *reinterpret_cast<const float4*>(edge_W + lane * 4);
  float s = ef.x * wv.x + ef.y * wv.y + ef.z * wv.z + ef.w * wv.w;
#pragma unroll
  for (int off = 32; off > 0; off >>= 1) s += __shfl_down(s, off);
  if (lane == 0) coeff[widx] = s + edge_b[0];
}

// ---------------------------------------------------------------------------
// Kernel 2: zero the per-node counters
// ---------------------------------------------------------------------------
__global__ void k_zero(int* __restrict__ p, int n) {
  const int i = blockIdx.x * blockDim.x + threadIdx.x;
  if (i < n) p[i] = 0;
}

// ---------------------------------------------------------------------------
// Kernel 3: build per-(b,node) incoming-edge lists (CSR with fixed capacity).
// Order within a list is non-deterministic (atomicAdd), but max-reduce is
// order-independent -> output deterministic.
// ---------------------------------------------------------------------------
__global__ __launch_bounds__(256) void k_build(const int* __restrict__ cfg,
                                               int* __restrict__ cnt,
                                               int* __restrict__ lst) {
  const int i = blockIdx.x * blockDim.x + threadIdx.x;  // flat b*E+e
  if (i >= BB * EE) return;
  const int b = i >> 16;            // E = 65536
  const int e = i & 0xFFFF;
  const int tgt = cfg[(size_t)i * 2 + 1];
  const int slot = b * NN + tgt;
  const int p = atomicAdd(&cnt[slot], 1);
  if (p < CAP) lst[(size_t)slot * CAP + p] = e;
}

__device__ __forceinline__ float f4c(const float4& v, int c) {
  switch (c) {
    case 0: return v.x;
    case 1: return v.y;
    case 2: return v.z;
    default: return v.w;
  }
}

// ---------------------------------------------------------------------------
// Kernel 4 (fused): per block of 8 nodes:
//   stage 1: x[i,m,h] = node_fts + max_e coeff[e]*hint[src[e],m,h]  -> LDS (32KB)
//   stage 2: out[i,m,:] = x[i,m,:] @ W + bias   (fp32 VALU GEMM, 32x256 @ 256x256)
// Stage-2 layout: thread t -> column j0 = t&63 (+64k, k=0..3), row group rg = t>>6
// (rows rg*8..rg*8+7). LDS reads are wave-uniform (broadcast, conflict-free);
// W reads are lane-consecutive (coalesced, W fully L2-resident at 256KB).
// ---------------------------------------------------------------------------
__global__ __launch_bounds__(256) void k_fused(const int* __restrict__ cfg,
                                               const float* __restrict__ hint,
                                               const float* __restrict__ node_fts,
                                               const float* __restrict__ coeff,
                                               const int* __restrict__ cnt,
                                               const int* __restrict__ lst,
                                               const float* __restrict__ W,
                                               const float* __restrict__ bias,
                                               float* __restrict__ out) {
  __shared__ float xs[NPB * MM][HH];  // 32 KB

  const int t = threadIdx.x;
  const int blk = blockIdx.x;
  const int b = blk / (NN / NPB);
  const int n0 = (blk % (NN / NPB)) * NPB;
  const int m = t >> 6;   // 0..3
  const int hq = t & 63;  // float4 index along H

  const float NEG_INF = __int_as_float(0xff800000);

  // ---- stage 1: gather + coeff-scale + max + add node_fts ----
  for (int i = 0; i < NPB; ++i) {
    const int n = n0 + i;
    const int deg = min(cnt[b * NN + n], CAP);
    const int* el = lst + (size_t)(b * NN + n) * CAP;
    float4 acc = make_float4(NEG_INF, NEG_INF, NEG_INF, NEG_INF);
    for (int k = 0; k < deg; ++k) {
      const int e = el[k];
      const float c = coeff[b * EE + e];
      const int s = cfg[((size_t)(b * EE + e)) * 2];
      const float4 hv = *reinterpret_cast<const float4*>(
          hint + (((size_t)(b * NN + s) * MM + m) * HH) + hq * 4);
      acc.x = fmaxf(acc.x, c * hv.x);
      acc.y = fmaxf(acc.y, c * hv.y);
      acc.z = fmaxf(acc.z, c * hv.z);
      acc.w = fmaxf(acc.w, c * hv.w);
    }
    const float4 nf = *reinterpret_cast<const float4*>(
        node_fts + (((size_t)(b * NN + n) * MM + m) * HH) + hq * 4);
    float4 xv;
    xv.x = nf.x + acc.x;
    xv.y = nf.y + acc.y;
    xv.z = nf.z + acc.z;
    xv.w = nf.w + acc.w;
    *reinterpret_cast<float4*>(&xs[i * MM + m][hq * 4]) = xv;
  }
  __syncthreads();

  // ---- stage 2: [32 x 256] @ [256 x 256] fp32 GEMM ----
  const int j0 = t & 63;
  const int rg = t >> 6;  // rows rg*8 .. rg*8+7

  float acc2[4][8];
#pragma unroll
  for (int k = 0; k < 4; ++k)
#pragma unroll
    for (int r = 0; r < 8; ++r) acc2[k][r] = 0.0f;

  for (int hq2 = 0; hq2 < HH / 4; ++hq2) {
    float4 xv[8];
#pragma unroll
    for (int r = 0; r < 8; ++r)
      xv[r] = *reinterpret_cast<const float4*>(&xs[rg * 8 + r][hq2 * 4]);
#pragma unroll
    for (int hh = 0; hh < 4; ++hh) {
      const int h = hq2 * 4 + hh;
      float wv[4];
#pragma unroll
      for (int k = 0; k < 4; ++k) wv[k] = W[h * HH + j0 + 64 * k];
#pragma unroll
      for (int k = 0; k < 4; ++k) {
#pragma unroll
        for (int r = 0; r < 8; ++r) {
          acc2[k][r] = fmaf(f4c(xv[r], hh), wv[k], acc2[k][r]);
        }
      }
    }
  }

  // ---- write out (+bias) ----
#pragma unroll
  for (int k = 0; k < 4; ++k) {
    const float bj = bias[j0 + 64 * k];
#pragma unroll
    for (int r = 0; r < 8; ++r) {
      const int row = rg * 8 + r;
      const int i = row >> 2;
      const int m2 = row & 3;
      out[(((size_t)(b * NN + n0 + i) * MM + m2) * HH) + j0 + 64 * k] = acc2[k][r] + bj;
    }
  }
}

// ---------------------------------------------------------------------------
extern "C" void kernel_launch(void* const* d_in, const int* in_sizes, int n_in,
                              void* d_out, int out_size, void* d_ws, size_t ws_size,
                              hipStream_t stream) {
  const int* cfg = (const int*)d_in[0];          // [B,E,2]
  const float* hint = (const float*)d_in[1];     // [B,N,M,H]
  const float* node_fts = (const float*)d_in[2]; // [B,N,M,H]
  const float* edge_fts = (const float*)d_in[3]; // [B,E,H]
  const float* edge_W = (const float*)d_in[4];   // [H,1]
  const float* edge_b = (const float*)d_in[5];   // [1]
  const float* update_W = (const float*)d_in[6]; // [H,H]
  const float* update_b = (const float*)d_in[7]; // [H]
  float* out = (float*)d_out;

  char* ws = (char*)d_ws;
  float* coeff = (float*)ws;                                        // B*E floats   (512 KB)
  int* cnt = (int*)(ws + (size_t)BB * EE * 4);                      // B*N ints     (32 KB)
  int* lst = (int*)(ws + (size_t)BB * EE * 4 + (size_t)BB * NN * 4);// B*N*CAP ints (1 MB)

  // 1) per-edge coefficients (one wave per edge)
  k_coeff<<<(BB * EE) / 4, 256, 0, stream>>>(edge_fts, edge_W, edge_b, coeff);
  // 2) zero counters
  k_zero<<<(BB * NN + 255) / 256, 256, 0, stream>>>(cnt, BB * NN);
  // 3) build per-node incoming edge lists
  k_build<<<(BB * EE) / 256, 256, 0, stream>>>(cfg, cnt, lst);
  // 4) fused gather-max + linear update
  k_fused<<<(BB * NN) / NPB, 256, 0, stream>>>(cfg, hint, node_fts, coeff, cnt, lst,
                                               update_W, update_b, out);
}

// Round 3
// 156.340 us; speedup vs baseline: 1.1645x; 1.1645x over previous
//
#include <hip/hip_runtime.h>

// Problem constants (fixed by the reference setup)
#define BB 2
#define NN 4096
#define EE 65536
#define MM 4
#define HH 256
#define CAP 32   // actual in-degree is exactly 16 per node; 32 gives safety margin
#define NPB 8    // nodes per block in the fused kernel

// ---------------------------------------------------------------------------
// Kernel 1: zero the per-node counters
// ---------------------------------------------------------------------------
__global__ void k_zero(int* __restrict__ p, int n) {
  const int i = blockIdx.x * blockDim.x + threadIdx.x;
  if (i < n) p[i] = 0;
}

// ---------------------------------------------------------------------------
// Kernel 2 (fused coeff+build): one 64-lane wave per edge.
//   coeff = edge_fts[b,e,:] . edge_W + edge_b   (float4/lane + shuffle reduce)
//   lane 0: slot = (b, tgt); p = atomicAdd(cnt); packed[slot*CAP+p] = {src, coeff}
// List order is non-deterministic (atomicAdd) but max-reduce is commutative ->
// final output deterministic.
// ---------------------------------------------------------------------------
__global__ __launch_bounds__(256) void k_coeff_build(const float* __restrict__ edge_fts,
                                                     const float* __restrict__ edge_W,
                                                     const float* __restrict__ edge_b,
                                                     const int* __restrict__ cfg,
                                                     int* __restrict__ cnt,
                                                     int2* __restrict__ packed) {
  const int gid = blockIdx.x * blockDim.x + threadIdx.x;
  const int widx = gid >> 6;   // flat edge index b*E+e
  const int lane = gid & 63;
  if (widx >= BB * EE) return;
  const float4 ef = *reinterpret_cast<const float4*>(edge_fts + (size_t)widx * HH + lane * 4);
  const float4 wv = *reinterpret_cast<const float4*>(edge_W + lane * 4);
  float s = ef.x * wv.x + ef.y * wv.y + ef.z * wv.z + ef.w * wv.w;
#pragma unroll
  for (int off = 32; off > 0; off >>= 1) s += __shfl_down(s, off);
  if (lane == 0) {
    const int b = widx >> 16;  // E = 65536
    const int2 st = *reinterpret_cast<const int2*>(cfg + (size_t)widx * 2);  // (src, tgt)
    const int slot = b * NN + st.y;
    const int p = atomicAdd(&cnt[slot], 1);
    if (p < CAP) {
      int2 v;
      v.x = st.x;                              // src node
      v.y = __float_as_int(s + edge_b[0]);     // coeff
      packed[(size_t)slot * CAP + p] = v;
    }
  }
}

__device__ __forceinline__ float4 fmax4(const float4& a, const float4& b) {
  return make_float4(fmaxf(a.x, b.x), fmaxf(a.y, b.y), fmaxf(a.z, b.z), fmaxf(a.w, b.w));
}

// ---------------------------------------------------------------------------
// Kernel 3 (fused): per block of 8 nodes:
//   stage 0: stage the block's 8x16 (src,coeff) pairs into LDS
//   stage 1: x[i,m,h] = node_fts + max_e coeff[e]*hint[src[e],m,h]  -> LDS (32KB)
//            fast path (deg==16): 16 INDEPENDENT float4 loads in flight, fmax tree
//   stage 2: out = x @ W + bias  (fp32 VALU GEMM, 32x256 @ 256x256)
//            thread t -> rows (t>>6)*8..+7, cols j0=(t&63)*4..+3 (float4 W/out)
// ---------------------------------------------------------------------------
__global__ __launch_bounds__(256) void k_fused(const float* __restrict__ hint,
                                               const float* __restrict__ node_fts,
                                               const int* __restrict__ cnt,
                                               const int2* __restrict__ packed,
                                               const float* __restrict__ W,
                                               const float* __restrict__ bias,
                                               float* __restrict__ out) {
  __shared__ float xs[NPB * MM][HH];  // 32 KB
  __shared__ int ssrc[NPB][16];
  __shared__ float scf[NPB][16];
  __shared__ int sdeg[NPB];

  const int t = threadIdx.x;
  const int blk = blockIdx.x;
  const int b = blk / (NN / NPB);
  const int n0 = (blk % (NN / NPB)) * NPB;
  const int m = t >> 6;   // 0..3 (wave id)
  const int hq = t & 63;  // float4 index along H

  const float NEG_INF = __int_as_float(0xff800000);

  // ---- stage 0: stage (src,coeff) pairs ----
  if (t < NPB) sdeg[t] = cnt[b * NN + n0 + t];
  __syncthreads();
  if (t < NPB * 16) {
    const int i = t >> 4, k = t & 15;
    if (k < min(sdeg[i], CAP)) {
      const int2 v = packed[(size_t)(b * NN + n0 + i) * CAP + k];
      ssrc[i][k] = v.x;
      scf[i][k] = __int_as_float(v.y);
    }
  }
  __syncthreads();

  // per-thread base into hint for (b, m, hq)
  const float* hb = hint + (size_t)b * NN * MM * HH + m * HH + hq * 4;

  // ---- stage 1: gather + coeff-scale + max + add node_fts ----
#pragma unroll 1
  for (int i = 0; i < NPB; ++i) {
    const int deg = sdeg[i];
    float4 acc;
    if (deg == 16) {
      float4 hv[16];
#pragma unroll
      for (int k = 0; k < 16; ++k) {
        const int s = ssrc[i][k];
        hv[k] = *reinterpret_cast<const float4*>(hb + (size_t)s * (MM * HH));
      }
#pragma unroll
      for (int k = 0; k < 16; ++k) {
        const float c = scf[i][k];
        hv[k].x *= c; hv[k].y *= c; hv[k].z *= c; hv[k].w *= c;
      }
#pragma unroll
      for (int off = 8; off > 0; off >>= 1)
#pragma unroll
        for (int k = 0; k < 8; ++k)
          if (k < off) hv[k] = fmax4(hv[k], hv[k + off]);
      acc = hv[0];
    } else {
      // generic path (deg != 16): read packed list straight from global
      acc = make_float4(NEG_INF, NEG_INF, NEG_INF, NEG_INF);
      const int2* pl = packed + (size_t)(b * NN + n0 + i) * CAP;
      const int d = min(deg, CAP);
      for (int k = 0; k < d; ++k) {
        const int2 v = pl[k];
        const float c = __int_as_float(v.y);
        const float4 hv = *reinterpret_cast<const float4*>(hb + (size_t)v.x * (MM * HH));
        acc.x = fmaxf(acc.x, c * hv.x);
        acc.y = fmaxf(acc.y, c * hv.y);
        acc.z = fmaxf(acc.z, c * hv.z);
        acc.w = fmaxf(acc.w, c * hv.w);
      }
    }
    const float4 nf = *reinterpret_cast<const float4*>(
        node_fts + (((size_t)(b * NN + n0 + i) * MM + m) * HH) + hq * 4);
    float4 xv;
    xv.x = nf.x + acc.x;
    xv.y = nf.y + acc.y;
    xv.z = nf.z + acc.z;
    xv.w = nf.w + acc.w;
    *reinterpret_cast<float4*>(&xs[i * MM + m][hq * 4]) = xv;
  }
  __syncthreads();

  // ---- stage 2: [32 x 256] @ [256 x 256] fp32 GEMM ----
  const int j0 = (t & 63) * 4;  // 4 consecutive output columns
  const int rg = t >> 6;        // rows rg*8 .. rg*8+7

  float4 acc2[8];
#pragma unroll
  for (int r = 0; r < 8; ++r) acc2[r] = make_float4(0.f, 0.f, 0.f, 0.f);

  for (int hq2 = 0; hq2 < HH / 4; ++hq2) {
    float4 xv[8];
#pragma unroll
    for (int r = 0; r < 8; ++r)
      xv[r] = *reinterpret_cast<const float4*>(&xs[rg * 8 + r][hq2 * 4]);
#pragma unroll
    for (int hh = 0; hh < 4; ++hh) {
      const float4 wq = *reinterpret_cast<const float4*>(W + (size_t)(hq2 * 4 + hh) * HH + j0);
#pragma unroll
      for (int r = 0; r < 8; ++r) {
        const float xr = (hh == 0) ? xv[r].x : (hh == 1) ? xv[r].y : (hh == 2) ? xv[r].z : xv[r].w;
        acc2[r].x = fmaf(xr, wq.x, acc2[r].x);
        acc2[r].y = fmaf(xr, wq.y, acc2[r].y);
        acc2[r].z = fmaf(xr, wq.z, acc2[r].z);
        acc2[r].w = fmaf(xr, wq.w, acc2[r].w);
      }
    }
  }

  // ---- write out (+bias), float4 per row ----
  const float4 bq = *reinterpret_cast<const float4*>(bias + j0);
#pragma unroll
  for (int r = 0; r < 8; ++r) {
    const int row = rg * 8 + r;
    const int i = row >> 2;
    const int m2 = row & 3;
    float4 o;
    o.x = acc2[r].x + bq.x;
    o.y = acc2[r].y + bq.y;
    o.z = acc2[r].z + bq.z;
    o.w = acc2[r].w + bq.w;
    *reinterpret_cast<float4*>(out + (((size_t)(b * NN + n0 + i) * MM + m2) * HH) + j0) = o;
  }
}

// ---------------------------------------------------------------------------
extern "C" void kernel_launch(void* const* d_in, const int* in_sizes, int n_in,
                              void* d_out, int out_size, void* d_ws, size_t ws_size,
                              hipStream_t stream) {
  const int* cfg = (const int*)d_in[0];          // [B,E,2]
  const float* hint = (const float*)d_in[1];     // [B,N,M,H]
  const float* node_fts = (const float*)d_in[2]; // [B,N,M,H]
  const float* edge_fts = (const float*)d_in[3]; // [B,E,H]
  const float* edge_W = (const float*)d_in[4];   // [H,1]
  const float* edge_b = (const float*)d_in[5];   // [1]
  const float* update_W = (const float*)d_in[6]; // [H,H]
  const float* update_b = (const float*)d_in[7]; // [H]
  float* out = (float*)d_out;

  char* ws = (char*)d_ws;
  int* cnt = (int*)ws;                                   // B*N ints   (32 KB)
  int2* packed = (int2*)(ws + (size_t)BB * NN * 4);      // B*N*CAP int2 (2 MB)

  // 1) zero counters
  k_zero<<<(BB * NN + 255) / 256, 256, 0, stream>>>(cnt, BB * NN);
  // 2) per-edge coefficient + build packed (src,coeff) lists
  k_coeff_build<<<(BB * EE) / 4, 256, 0, stream>>>(edge_fts, edge_W, edge_b, cfg, cnt, packed);
  // 3) fused gather-max + linear update
  k_fused<<<(BB * NN) / NPB, 256, 0, stream>>>(hint, node_fts, cnt, packed,
                                               update_W, update_b, out);
}